// Round 4
// baseline (461.377 us; speedup 1.0000x reference)
//
#include <hip/hip_runtime.h>

// Problem: B=4, T=2048, C=512, H=8, D=64.
// Inputs/outputs fp32 (per reference dtypes); internal pipeline bf16.
typedef __bf16 bf16x8 __attribute__((ext_vector_type(8)));
typedef float f32x4 __attribute__((ext_vector_type(4)));
typedef unsigned short ushort8_t __attribute__((ext_vector_type(8)));

#define MFMA16(a, b, c) __builtin_amdgcn_mfma_f32_16x16x32_bf16(a, b, c, 0, 0, 0)
#define EXPC 0.18033688011112042f   // log2(e)/8 :  exp(att) = exp2(acc * EXPC)

__device__ __forceinline__ float bf2f(unsigned short u) {
    union { unsigned int i; float f; } c; c.i = ((unsigned int)u) << 16; return c.f;
}
// native HW convert (RNE) — ~1 VALU op vs ~5 for the manual bit recipe
__device__ __forceinline__ unsigned short f2bf(float f) {
    union { __bf16 h; unsigned short u; } c; c.h = (__bf16)f; return c.u;
}

// ---------------------------------------------------------------- W = qkv + delta (fp32 in -> bf16 W, W^T)
__global__ void prep_w(const float* __restrict__ qkv,
                       const float* __restrict__ delta,
                       unsigned short* __restrict__ W,
                       unsigned short* __restrict__ WT) {
    __shared__ __align__(16) unsigned short tile[64][72];
    const int r0 = blockIdx.x * 64, c0 = blockIdx.y * 64;
    const int rl = threadIdx.x >> 2;
    const int cg = (threadIdx.x & 3) * 16;
    const size_t idx = (size_t)(r0 + rl) * 512 + c0 + cg;
    ushort8_t o0, o1;
    for (int j = 0; j < 8; ++j) {
        o0[j] = f2bf(qkv[idx + j] + delta[idx + j]);
        o1[j] = f2bf(qkv[idx + 8 + j] + delta[idx + 8 + j]);
        tile[rl][cg + j] = o0[j];
        tile[rl][cg + 8 + j] = o1[j];
    }
    *(ushort8_t*)(W + idx) = o0;
    *(ushort8_t*)(W + idx + 8) = o1;
    __syncthreads();
    const int cl = threadIdx.x >> 2;
    const int rg = (threadIdx.x & 3) * 16;
    ushort8_t t0, t1;
    for (int j = 0; j < 8; ++j) {
        t0[j] = tile[rg + j][cl];
        t1[j] = tile[rg + 8 + j][cl];
    }
    const size_t tidx = (size_t)(c0 + cl) * 512 + r0 + rg;
    *(ushort8_t*)(WT + tidx) = t0;
    *(ushort8_t*)(WT + tidx + 8) = t1;
}

// ---------------------------------------------------------------- C[m,n] = sum_k A[m,k]*B[n,k]
// aF32: A fp32 (convert to bf16 during staging); else bf16.
// mode 0: C row-major (M x N) fp32.  mode 1: C scattered into (b,h,t,d) bf16.
__global__ __launch_bounds__(256) void gemm_bt(const void* __restrict__ Ap,
                                               const unsigned short* __restrict__ Bm,
                                               void* __restrict__ Cp,
                                               int M, int N, int K, int mode, int aF32) {
    __shared__ __align__(16) unsigned short As[64][40];
    __shared__ __align__(16) unsigned short Bs[64][40];
    const int tid = threadIdx.x;
    const int wid = tid >> 6, lane = tid & 63;
    const int quad = lane >> 4, l16 = lane & 15;
    const int m0 = blockIdx.x * 64, n0 = blockIdx.y * 64;
    const int waveM = (wid & 1) * 32, waveN = (wid >> 1) * 32;
    const int ldRow = tid >> 2;
    const int ldCol = (tid & 3) * 8;
    f32x4 acc[2][2] = {};
    for (int k0 = 0; k0 < K; k0 += 32) {
        ushort8_t av;
        if (aF32) {
            const float* Af = (const float*)Ap + (size_t)(m0 + ldRow) * K + k0 + ldCol;
            float4 f0 = *(const float4*)(Af);
            float4 f1 = *(const float4*)(Af + 4);
            av[0] = f2bf(f0.x); av[1] = f2bf(f0.y); av[2] = f2bf(f0.z); av[3] = f2bf(f0.w);
            av[4] = f2bf(f1.x); av[5] = f2bf(f1.y); av[6] = f2bf(f1.z); av[7] = f2bf(f1.w);
        } else {
            av = *(const ushort8_t*)((const unsigned short*)Ap + (size_t)(m0 + ldRow) * K + k0 + ldCol);
        }
        ushort8_t bv = *(const ushort8_t*)(Bm + (size_t)(n0 + ldRow) * K + k0 + ldCol);
        __syncthreads();
        *(ushort8_t*)(&As[ldRow][ldCol]) = av;
        *(ushort8_t*)(&Bs[ldRow][ldCol]) = bv;
        __syncthreads();
        bf16x8 a[2], b[2];
        a[0] = *(const bf16x8*)(&As[waveM + l16][quad * 8]);
        a[1] = *(const bf16x8*)(&As[waveM + 16 + l16][quad * 8]);
        b[0] = *(const bf16x8*)(&Bs[waveN + l16][quad * 8]);
        b[1] = *(const bf16x8*)(&Bs[waveN + 16 + l16][quad * 8]);
        for (int mt = 0; mt < 2; ++mt)
            for (int nt = 0; nt < 2; ++nt)
                acc[mt][nt] = MFMA16(a[mt], b[nt], acc[mt][nt]);
    }
    for (int mt = 0; mt < 2; ++mt)
        for (int nt = 0; nt < 2; ++nt)
            for (int r = 0; r < 4; ++r) {
                int gm = m0 + waveM + mt * 16 + quad * 4 + r;   // C/D: row = quad*4+reg
                int gn = n0 + waveN + nt * 16 + l16;            //       col = lane&15
                float v = acc[mt][nt][r];
                if (mode == 0) {
                    ((float*)Cp)[(size_t)gm * N + gn] = v;
                } else {
                    size_t oidx = ((size_t)((gm >> 11) * 8 + (gn >> 6)) * 2048 + (gm & 2047)) * 64 + (gn & 63);
                    ((unsigned short*)Cp)[oidx] = f2bf(v);
                }
            }
}

// ---------------------------------------------------------------- RMSNorm: n1,n2 (bh,t,d) bf16; n3 transposed (bh,d,t) bf16
__global__ void rms_prepare(const unsigned short* __restrict__ w,
                            const float* __restrict__ g1,
                            const float* __restrict__ g2,
                            const float* __restrict__ g3,
                            unsigned short* __restrict__ n1,
                            unsigned short* __restrict__ n2,
                            unsigned short* __restrict__ n3t) {
    __shared__ __align__(16) unsigned short tile[64][72];
    const int bh = blockIdx.y;
    const int t0 = blockIdx.x * 64;
    const int tl = threadIdx.x >> 2;
    const int dg = (threadIdx.x & 3) * 16;
    const size_t rowbase = ((size_t)bh * 2048 + t0 + tl) * 64;
    ushort8_t w0 = *(const ushort8_t*)(w + rowbase + dg);
    ushort8_t w1 = *(const ushort8_t*)(w + rowbase + dg + 8);
    float v[16];
    for (int j = 0; j < 8; ++j) { v[j] = bf2f(w0[j]); v[8 + j] = bf2f(w1[j]); }
    float ss = 0.f;
    for (int j = 0; j < 16; ++j) ss += v[j] * v[j];
    ss += __shfl_xor(ss, 1);
    ss += __shfl_xor(ss, 2);                       // 4 lanes per row share the sum
    const float inv = rsqrtf(ss * (1.0f / 64.0f) + 1.1920929e-07f);
    ushort8_t a0, a1, b0, b1;
    for (int j = 0; j < 16; ++j) {
        int d = dg + j;
        float nb = v[j] * inv;
        unsigned short x1 = f2bf(nb * g1[d]);
        unsigned short x2 = f2bf(nb * g2[d]);
        unsigned short x3 = f2bf(nb * g3[d]);
        if (j < 8) { a0[j] = x1; b0[j] = x2; } else { a1[j - 8] = x1; b1[j - 8] = x2; }
        tile[tl][d] = x3;
    }
    *(ushort8_t*)(n1 + rowbase + dg) = a0;
    *(ushort8_t*)(n1 + rowbase + dg + 8) = a1;
    *(ushort8_t*)(n2 + rowbase + dg) = b0;
    *(ushort8_t*)(n2 + rowbase + dg + 8) = b1;
    __syncthreads();
    const int dr = threadIdx.x >> 2;
    const int tg = (threadIdx.x & 3) * 16;
    ushort8_t o0, o1;
    for (int j = 0; j < 8; ++j) {
        o0[j] = tile[tg + j][dr];
        o1[j] = tile[tg + 8 + j][dr];
    }
    const size_t obase = ((size_t)bh * 64 + dr) * 2048 + t0 + tg;
    *(ushort8_t*)(n3t + obase) = o0;
    *(ushort8_t*)(n3t + obase + 8) = o1;
}

// ---------------------------------------------------------------- E = exp(att): row sums + per-block (64-row) col partial sums.
// att in [-8,8] (unit-RMS rows) -> exp fp32-safe without max subtraction.
__global__ __launch_bounds__(256) void att_sums(const unsigned short* __restrict__ n1,
                                                const unsigned short* __restrict__ n2,
                                                float* __restrict__ rowRinv,
                                                float* __restrict__ colPart) {
    __shared__ float colAcc[2048];
    const int bh = blockIdx.y;
    const int tid = threadIdx.x;
    const int lane = tid & 63, wid = tid >> 6;
    const int quad = lane >> 4, l16 = lane & 15;
    for (int i = tid; i < 2048; i += 256) colAcc[i] = 0.f;
    __syncthreads();
    const int r0 = blockIdx.x * 64 + wid * 16;
    const size_t base = (size_t)bh * 2048 * 64;
    const unsigned short* Ar = n1 + base + (size_t)(r0 + l16) * 64 + quad * 8;
    bf16x8 a0 = *(const bf16x8*)(Ar);
    bf16x8 a1 = *(const bf16x8*)(Ar + 32);
    float rsum[4] = {};
    for (int j0 = 0; j0 < 2048; j0 += 32) {
        for (int jt = 0; jt < 2; ++jt) {
            const int j = j0 + jt * 16;
            const unsigned short* Br = n2 + base + (size_t)(j + l16) * 64 + quad * 8;
            bf16x8 b0 = *(const bf16x8*)(Br);
            bf16x8 b1 = *(const bf16x8*)(Br + 32);
            f32x4 acc = {0.f, 0.f, 0.f, 0.f};
            acc = MFMA16(a0, b0, acc);
            acc = MFMA16(a1, b1, acc);
            float ce = 0.f;
            for (int r = 0; r < 4; ++r) {
                float E = exp2f(acc[r] * EXPC);
                rsum[r] += E;
                ce += E;
            }
            ce += __shfl_xor(ce, 16);
            ce += __shfl_xor(ce, 32);           // sum over quads -> col partial over 16 rows
            if (lane < 16) atomicAdd(&colAcc[j + l16], ce);
        }
    }
    for (int r = 0; r < 4; ++r) {
        float s = rsum[r];
        s += __shfl_xor(s, 1); s += __shfl_xor(s, 2);
        s += __shfl_xor(s, 4); s += __shfl_xor(s, 8);   // reduce over 16 col-lanes
        if (l16 == 0)
            rowRinv[(size_t)bh * 2048 + r0 + quad * 4 + r] = 1.0f / s;
    }
    __syncthreads();
    float4* cp = (float4*)(colPart + ((size_t)bh * 32 + blockIdx.x) * 2048);
    for (int i = tid; i < 512; i += 256) cp[i] = *(float4*)(&colAcc[i * 4]);
}

// ---------------------------------------------------------------- colRinv = 1 / sum over 32 block-partials
__global__ void col_reduce(const float* __restrict__ colPart, float* __restrict__ colRinv) {
    const int bh = blockIdx.x >> 3;
    const int j = (blockIdx.x & 7) * 256 + threadIdx.x;
    const float* p = colPart + (size_t)bh * 32 * 2048 + j;
    float s = 0.f;
    for (int b = 0; b < 32; ++b) s += p[b * 2048];
    colRinv[(size_t)bh * 2048 + j] = 1.0f / s;
}

// ---------------------------------------------------------------- p = exp(att)*(rinv_row + rinv_col); y^T += n3^T p^T; y -> (b,t,h,d) bf16
__global__ __launch_bounds__(256) void att_apply(const unsigned short* __restrict__ n1,
                                                 const unsigned short* __restrict__ n2,
                                                 const unsigned short* __restrict__ n3t,
                                                 const float* __restrict__ rowRinv,
                                                 const float* __restrict__ colRinv,
                                                 unsigned short* __restrict__ ybuf) {
    __shared__ float sC[2048];
    __shared__ __align__(16) unsigned short pbuf[4][16][40];
    __shared__ __align__(16) float ytr[4][64][17];
    const int bh = blockIdx.y;
    const int bb = bh >> 3, hh = bh & 7;
    const int tid = threadIdx.x;
    const int lane = tid & 63, wid = tid >> 6;
    const int quad = lane >> 4, l16 = lane & 15;
    const size_t sbase = (size_t)bh * 2048;
    for (int i = tid; i < 2048; i += 256) sC[i] = colRinv[sbase + i];
    __syncthreads();
    const int r0 = blockIdx.x * 64 + wid * 16;
    const size_t base = sbase * 64;
    const unsigned short* Ar = n1 + base + (size_t)(r0 + l16) * 64 + quad * 8;
    bf16x8 a0 = *(const bf16x8*)(Ar);
    bf16x8 a1 = *(const bf16x8*)(Ar + 32);
    float rR[4];
    for (int r = 0; r < 4; ++r)
        rR[r] = rowRinv[sbase + r0 + quad * 4 + r];
    f32x4 yacc[4] = {};
    const unsigned short* n3base = n3t + (size_t)bh * 64 * 2048;
    for (int j0 = 0; j0 < 2048; j0 += 32) {
        for (int jt = 0; jt < 2; ++jt) {
            const int j = j0 + jt * 16;
            const unsigned short* Br = n2 + base + (size_t)(j + l16) * 64 + quad * 8;
            bf16x8 b0 = *(const bf16x8*)(Br);
            bf16x8 b1 = *(const bf16x8*)(Br + 32);
            f32x4 acc = {0.f, 0.f, 0.f, 0.f};
            acc = MFMA16(a0, b0, acc);
            acc = MFMA16(a1, b1, acc);
            const float cinv = sC[j + l16];
            for (int r = 0; r < 4; ++r) {
                float E = exp2f(acc[r] * EXPC);
                float p = E * (rR[r] + cinv);
                pbuf[wid][quad * 4 + r][jt * 16 + l16] = f2bf(p);   // C-layout -> [i][j]
            }
        }
        // per-wave LDS round-trip: read P as B-operand (n = i, k = 32 local j)
        bf16x8 pf = *(const bf16x8*)(&pbuf[wid][l16][quad * 8]);
        for (int dt = 0; dt < 4; ++dt) {
            bf16x8 af = *(const bf16x8*)(n3base + (size_t)(dt * 16 + l16) * 2048 + j0 + quad * 8);
            yacc[dt] = MFMA16(af, pf, yacc[dt]);
        }
    }
    // yacc = y^T tile (64 d x 16 i); transpose via wave-private LDS, store (b,t,h,d) bf16
    for (int dt = 0; dt < 4; ++dt)
        for (int r = 0; r < 4; ++r)
            ytr[wid][dt * 16 + quad * 4 + r][l16] = yacc[dt][r];
    for (int it = 0; it < 2; ++it) {
        int row = it * 8 + (lane >> 3);
        int dgp = (lane & 7) * 8;
        ushort8_t pk;
        for (int j = 0; j < 8; ++j) pk[j] = f2bf(ytr[wid][dgp + j][row]);
        int t = r0 + row;
        size_t oidx = ((size_t)(bb * 2048 + t) * 512) + hh * 64 + dgp;
        *(ushort8_t*)(ybuf + oidx) = pk;
    }
}

extern "C" void kernel_launch(void* const* d_in, const int* in_sizes, int n_in,
                              void* d_out, int out_size, void* d_ws, size_t ws_size,
                              hipStream_t stream) {
    const float* x   = (const float*)d_in[0];
    const float* dlt = (const float*)d_in[1];
    const float* qkv = (const float*)d_in[2];
    const float* g1  = (const float*)d_in[3];
    const float* g2  = (const float*)d_in[4];
    const float* g3  = (const float*)d_in[5];
    float* out = (float*)d_out;
    char* ws = (char*)d_ws;
    // workspace layout (33.5 MiB). The 8 MiB region at +1 MiB is reused thrice:
    // wb (dead after rms_prepare) -> colPart (dead after col_reduce) -> yb.
    unsigned short* W   = (unsigned short*)(ws);
    unsigned short* WT  = (unsigned short*)(ws + 524288);
    unsigned short* wb  = (unsigned short*)(ws + 1048576);
    float*          colPart = (float*)(ws + 1048576);
    unsigned short* yb  = wb;
    unsigned short* n1  = (unsigned short*)(ws + 9437184);
    unsigned short* n2  = (unsigned short*)(ws + 17825792);
    unsigned short* n3t = (unsigned short*)(ws + 26214400);
    float* rowRinv = (float*)(ws + 34603008);
    float* colRinv = (float*)(ws + 34865152);

    prep_w<<<dim3(8, 8), 256, 0, stream>>>(qkv, dlt, W, WT);
    gemm_bt<<<dim3(128, 8), 256, 0, stream>>>(x, W, wb, 8192, 512, 512, 1, 1);
    rms_prepare<<<dim3(32, 32), 256, 0, stream>>>(wb, g1, g2, g3, n1, n2, n3t);
    att_sums<<<dim3(32, 32), 256, 0, stream>>>(n1, n2, rowRinv, colPart);
    col_reduce<<<256, 256, 0, stream>>>(colPart, colRinv);
    att_apply<<<dim3(32, 32), 256, 0, stream>>>(n1, n2, n3t, rowRinv, colRinv, yb);
    gemm_bt<<<dim3(128, 8), 256, 0, stream>>>(yb, WT, out, 8192, 512, 512, 0, 0);
}

// Round 5
// 295.244 us; speedup vs baseline: 1.5627x; 1.5627x over previous
//
#include <hip/hip_runtime.h>

// Problem: B=4, T=2048, C=512, H=8, D=64.
// Inputs/outputs fp32 (per reference dtypes); internal pipeline bf16.
typedef __bf16 bf16x8 __attribute__((ext_vector_type(8)));
typedef float f32x4 __attribute__((ext_vector_type(4)));
typedef unsigned short ushort8_t __attribute__((ext_vector_type(8)));

#define MFMA16(a, b, c) __builtin_amdgcn_mfma_f32_16x16x32_bf16(a, b, c, 0, 0, 0)
#define EXPC 0.18033688011112042f   // log2(e)/8 :  exp(att) = exp2(acc * EXPC)

__device__ __forceinline__ float bf2f(unsigned short u) {
    union { unsigned int i; float f; } c; c.i = ((unsigned int)u) << 16; return c.f;
}
// native HW convert (RNE)
__device__ __forceinline__ unsigned short f2bf(float f) {
    union { __bf16 h; unsigned short u; } c; c.h = (__bf16)f; return c.u;
}

// ---------------------------------------------------------------- W = qkv + delta (fp32 in -> bf16 W, W^T)
__global__ void prep_w(const float* __restrict__ qkv,
                       const float* __restrict__ delta,
                       unsigned short* __restrict__ W,
                       unsigned short* __restrict__ WT) {
    __shared__ __align__(16) unsigned short tile[64][72];
    const int r0 = blockIdx.x * 64, c0 = blockIdx.y * 64;
    const int rl = threadIdx.x >> 2;
    const int cg = (threadIdx.x & 3) * 16;
    const size_t idx = (size_t)(r0 + rl) * 512 + c0 + cg;
    ushort8_t o0, o1;
    for (int j = 0; j < 8; ++j) {
        o0[j] = f2bf(qkv[idx + j] + delta[idx + j]);
        o1[j] = f2bf(qkv[idx + 8 + j] + delta[idx + 8 + j]);
        tile[rl][cg + j] = o0[j];
        tile[rl][cg + 8 + j] = o1[j];
    }
    *(ushort8_t*)(W + idx) = o0;
    *(ushort8_t*)(W + idx + 8) = o1;
    __syncthreads();
    const int cl = threadIdx.x >> 2;
    const int rg = (threadIdx.x & 3) * 16;
    ushort8_t t0, t1;
    for (int j = 0; j < 8; ++j) {
        t0[j] = tile[rg + j][cl];
        t1[j] = tile[rg + 8 + j][cl];
    }
    const size_t tidx = (size_t)(c0 + cl) * 512 + r0 + rg;
    *(ushort8_t*)(WT + tidx) = t0;
    *(ushort8_t*)(WT + tidx + 8) = t1;
}

// ---------------------------------------------------------------- C[m,n] = sum_k A[m,k]*B[n,k]
// aF32: A fp32 (convert to bf16 during staging); else bf16.
// mode 0: C row-major (M x N) fp32.  mode 1: C scattered into (b,h,t,d) bf16.
__global__ __launch_bounds__(256) void gemm_bt(const void* __restrict__ Ap,
                                               const unsigned short* __restrict__ Bm,
                                               void* __restrict__ Cp,
                                               int M, int N, int K, int mode, int aF32) {
    __shared__ __align__(16) unsigned short As[64][40];
    __shared__ __align__(16) unsigned short Bs[64][40];
    const int tid = threadIdx.x;
    const int wid = tid >> 6, lane = tid & 63;
    const int quad = lane >> 4, l16 = lane & 15;
    const int m0 = blockIdx.x * 64, n0 = blockIdx.y * 64;
    const int waveM = (wid & 1) * 32, waveN = (wid >> 1) * 32;
    const int ldRow = tid >> 2;
    const int ldCol = (tid & 3) * 8;
    f32x4 acc[2][2] = {};
    for (int k0 = 0; k0 < K; k0 += 32) {
        ushort8_t av;
        if (aF32) {
            const float* Af = (const float*)Ap + (size_t)(m0 + ldRow) * K + k0 + ldCol;
            float4 f0 = *(const float4*)(Af);
            float4 f1 = *(const float4*)(Af + 4);
            av[0] = f2bf(f0.x); av[1] = f2bf(f0.y); av[2] = f2bf(f0.z); av[3] = f2bf(f0.w);
            av[4] = f2bf(f1.x); av[5] = f2bf(f1.y); av[6] = f2bf(f1.z); av[7] = f2bf(f1.w);
        } else {
            av = *(const ushort8_t*)((const unsigned short*)Ap + (size_t)(m0 + ldRow) * K + k0 + ldCol);
        }
        ushort8_t bv = *(const ushort8_t*)(Bm + (size_t)(n0 + ldRow) * K + k0 + ldCol);
        __syncthreads();
        *(ushort8_t*)(&As[ldRow][ldCol]) = av;
        *(ushort8_t*)(&Bs[ldRow][ldCol]) = bv;
        __syncthreads();
        bf16x8 a[2], b[2];
        a[0] = *(const bf16x8*)(&As[waveM + l16][quad * 8]);
        a[1] = *(const bf16x8*)(&As[waveM + 16 + l16][quad * 8]);
        b[0] = *(const bf16x8*)(&Bs[waveN + l16][quad * 8]);
        b[1] = *(const bf16x8*)(&Bs[waveN + 16 + l16][quad * 8]);
        for (int mt = 0; mt < 2; ++mt)
            for (int nt = 0; nt < 2; ++nt)
                acc[mt][nt] = MFMA16(a[mt], b[nt], acc[mt][nt]);
    }
    for (int mt = 0; mt < 2; ++mt)
        for (int nt = 0; nt < 2; ++nt)
            for (int r = 0; r < 4; ++r) {
                int gm = m0 + waveM + mt * 16 + quad * 4 + r;   // C/D: row = quad*4+reg
                int gn = n0 + waveN + nt * 16 + l16;            //       col = lane&15
                float v = acc[mt][nt][r];
                if (mode == 0) {
                    ((float*)Cp)[(size_t)gm * N + gn] = v;
                } else {
                    size_t oidx = ((size_t)((gm >> 11) * 8 + (gn >> 6)) * 2048 + (gm & 2047)) * 64 + (gn & 63);
                    ((unsigned short*)Cp)[oidx] = f2bf(v);
                }
            }
}

// ---------------------------------------------------------------- RMSNorm: n1,n2 (bh,t,d) bf16; n3 transposed (bh,d,t) bf16
__global__ void rms_prepare(const unsigned short* __restrict__ w,
                            const float* __restrict__ g1,
                            const float* __restrict__ g2,
                            const float* __restrict__ g3,
                            unsigned short* __restrict__ n1,
                            unsigned short* __restrict__ n2,
                            unsigned short* __restrict__ n3t) {
    __shared__ __align__(16) unsigned short tile[64][72];
    const int bh = blockIdx.y;
    const int t0 = blockIdx.x * 64;
    const int tl = threadIdx.x >> 2;
    const int dg = (threadIdx.x & 3) * 16;
    const size_t rowbase = ((size_t)bh * 2048 + t0 + tl) * 64;
    ushort8_t w0 = *(const ushort8_t*)(w + rowbase + dg);
    ushort8_t w1 = *(const ushort8_t*)(w + rowbase + dg + 8);
    float v[16];
    for (int j = 0; j < 8; ++j) { v[j] = bf2f(w0[j]); v[8 + j] = bf2f(w1[j]); }
    float ss = 0.f;
    for (int j = 0; j < 16; ++j) ss += v[j] * v[j];
    ss += __shfl_xor(ss, 1);
    ss += __shfl_xor(ss, 2);                       // 4 lanes per row share the sum
    const float inv = rsqrtf(ss * (1.0f / 64.0f) + 1.1920929e-07f);
    ushort8_t a0, a1, b0, b1;
    for (int j = 0; j < 16; ++j) {
        int d = dg + j;
        float nb = v[j] * inv;
        unsigned short x1 = f2bf(nb * g1[d]);
        unsigned short x2 = f2bf(nb * g2[d]);
        unsigned short x3 = f2bf(nb * g3[d]);
        if (j < 8) { a0[j] = x1; b0[j] = x2; } else { a1[j - 8] = x1; b1[j - 8] = x2; }
        tile[tl][d] = x3;
    }
    *(ushort8_t*)(n1 + rowbase + dg) = a0;
    *(ushort8_t*)(n1 + rowbase + dg + 8) = a1;
    *(ushort8_t*)(n2 + rowbase + dg) = b0;
    *(ushort8_t*)(n2 + rowbase + dg + 8) = b1;
    __syncthreads();
    const int dr = threadIdx.x >> 2;
    const int tg = (threadIdx.x & 3) * 16;
    ushort8_t o0, o1;
    for (int j = 0; j < 8; ++j) {
        o0[j] = tile[tg + j][dr];
        o1[j] = tile[tg + 8 + j][dr];
    }
    const size_t obase = ((size_t)bh * 64 + dr) * 2048 + t0 + tg;
    *(ushort8_t*)(n3t + obase) = o0;
    *(ushort8_t*)(n3t + obase + 8) = o1;
}

// ---------------------------------------------------------------- E = exp(att): row sums + per-block col partials.
// 512 threads: waves 0-3 = rows r0..r0+128 x j[0,1024); waves 4-7 same rows x j[1024,2048).
// att in [-8,8] (unit-RMS rows) -> exp fp32-safe without max subtraction.
__global__ __launch_bounds__(512) void att_sums(const unsigned short* __restrict__ n1,
                                                const unsigned short* __restrict__ n2,
                                                float* __restrict__ rowRinv,
                                                float* __restrict__ colPart) {
    __shared__ float colAcc[2048];
    __shared__ float rowAcc[128];
    const int bh = blockIdx.y;
    const int tid = threadIdx.x;
    const int lane = tid & 63, wid = tid >> 6;
    const int rwid = wid & 3, jg = wid >> 2;
    const int quad = lane >> 4, l16 = lane & 15;
    for (int i = tid; i < 2048; i += 512) colAcc[i] = 0.f;
    if (tid < 128) rowAcc[tid] = 0.f;
    __syncthreads();
    const int r0 = blockIdx.x * 128 + rwid * 32;
    const size_t base = (size_t)bh * 2048 * 64;
    bf16x8 a[2][2];
    for (int rt = 0; rt < 2; ++rt) {
        const unsigned short* Ar = n1 + base + (size_t)(r0 + rt * 16 + l16) * 64 + quad * 8;
        a[rt][0] = *(const bf16x8*)(Ar);
        a[rt][1] = *(const bf16x8*)(Ar + 32);
    }
    float rsum[2][4] = {};
    const int jbase = jg * 1024;
    for (int j0 = jbase; j0 < jbase + 1024; j0 += 16) {
        const unsigned short* Br = n2 + base + (size_t)(j0 + l16) * 64 + quad * 8;
        bf16x8 b0 = *(const bf16x8*)(Br);
        bf16x8 b1 = *(const bf16x8*)(Br + 32);
        float ce = 0.f;
        for (int rt = 0; rt < 2; ++rt) {
            f32x4 acc = {0.f, 0.f, 0.f, 0.f};
            acc = MFMA16(a[rt][0], b0, acc);
            acc = MFMA16(a[rt][1], b1, acc);
            for (int r = 0; r < 4; ++r) {
                float E = exp2f(acc[r] * EXPC);
                rsum[rt][r] += E;
                ce += E;
            }
        }
        ce += __shfl_xor(ce, 16);
        ce += __shfl_xor(ce, 32);               // sum over quads -> col partial over 32 rows
        if (lane < 16) atomicAdd(&colAcc[j0 + l16], ce);
    }
    for (int rt = 0; rt < 2; ++rt)
        for (int r = 0; r < 4; ++r) {
            float s = rsum[rt][r];
            s += __shfl_xor(s, 1); s += __shfl_xor(s, 2);
            s += __shfl_xor(s, 4); s += __shfl_xor(s, 8);   // reduce over 16 col-lanes
            if (l16 == 0)
                atomicAdd(&rowAcc[rwid * 32 + rt * 16 + quad * 4 + r], s);  // merge 2 j-groups
        }
    __syncthreads();
    if (tid < 128)
        rowRinv[(size_t)bh * 2048 + blockIdx.x * 128 + tid] = 1.0f / rowAcc[tid];
    float4* cp = (float4*)(colPart + ((size_t)bh * 16 + blockIdx.x) * 2048);
    if (tid < 512) cp[tid] = *(float4*)(&colAcc[tid * 4]);
}

// ---------------------------------------------------------------- colRinv = 1 / sum over 16 block-partials
__global__ void col_reduce(const float* __restrict__ colPart, float* __restrict__ colRinv) {
    const int bh = blockIdx.x >> 3;
    const int j = (blockIdx.x & 7) * 256 + threadIdx.x;
    const float* p = colPart + (size_t)bh * 16 * 2048 + j;
    float s = 0.f;
    for (int b = 0; b < 16; ++b) s += p[b * 2048];
    colRinv[(size_t)bh * 2048 + j] = 1.0f / s;
}

// ---------------------------------------------------------------- p = exp(att)*(rinv_row + rinv_col); y^T += n3^T p^T; y -> (b,t,h,d) bf16
// 512 threads: waves 0-3 = rows x j[0,1024); waves 4-7 same rows x j[1024,2048).
// Partial y accumulators merged through the ytr LDS transpose.
__global__ __launch_bounds__(512) void att_apply(const unsigned short* __restrict__ n1,
                                                 const unsigned short* __restrict__ n2,
                                                 const unsigned short* __restrict__ n3t,
                                                 const float* __restrict__ rowRinv,
                                                 const float* __restrict__ colRinv,
                                                 unsigned short* __restrict__ ybuf) {
    __shared__ float sC[2048];
    __shared__ __align__(16) unsigned short pbuf[8][32][40];
    __shared__ __align__(16) float ytr[4][64][17];
    const int bh = blockIdx.y;
    const int bb = bh >> 3, hh = bh & 7;
    const int tid = threadIdx.x;
    const int lane = tid & 63, wid = tid >> 6;
    const int rwid = wid & 3, jg = wid >> 2;
    const int quad = lane >> 4, l16 = lane & 15;
    const size_t sbase = (size_t)bh * 2048;
    for (int i = tid; i < 2048; i += 512) sC[i] = colRinv[sbase + i];
    __syncthreads();
    const int r0 = blockIdx.x * 128 + rwid * 32;
    const size_t base = sbase * 64;
    bf16x8 a[2][2];
    float rR[2][4];
    for (int rt = 0; rt < 2; ++rt) {
        const unsigned short* Ar = n1 + base + (size_t)(r0 + rt * 16 + l16) * 64 + quad * 8;
        a[rt][0] = *(const bf16x8*)(Ar);
        a[rt][1] = *(const bf16x8*)(Ar + 32);
        for (int r = 0; r < 4; ++r)
            rR[rt][r] = rowRinv[sbase + r0 + rt * 16 + quad * 4 + r];
    }
    f32x4 yacc[2][4] = {};
    const unsigned short* n3base = n3t + (size_t)bh * 64 * 2048;
    const int jbase = jg * 1024;
    for (int j0 = jbase; j0 < jbase + 1024; j0 += 32) {
        for (int jt = 0; jt < 2; ++jt) {
            const int j = j0 + jt * 16;
            const unsigned short* Br = n2 + base + (size_t)(j + l16) * 64 + quad * 8;
            bf16x8 b0 = *(const bf16x8*)(Br);
            bf16x8 b1 = *(const bf16x8*)(Br + 32);
            const float cinv = sC[j + l16];
            for (int rt = 0; rt < 2; ++rt) {
                f32x4 acc = {0.f, 0.f, 0.f, 0.f};
                acc = MFMA16(a[rt][0], b0, acc);
                acc = MFMA16(a[rt][1], b1, acc);
                for (int r = 0; r < 4; ++r) {
                    float E = exp2f(acc[r] * EXPC);
                    float p = E * (rR[rt][r] + cinv);
                    pbuf[wid][rt * 16 + quad * 4 + r][jt * 16 + l16] = f2bf(p);
                }
            }
        }
        // per-wave LDS round-trip: read P as B-operand (n = i, k = local j in [0,32))
        bf16x8 pf0 = *(const bf16x8*)(&pbuf[wid][l16][quad * 8]);
        bf16x8 pf1 = *(const bf16x8*)(&pbuf[wid][16 + l16][quad * 8]);
        for (int dt = 0; dt < 4; ++dt) {
            bf16x8 af = *(const bf16x8*)(n3base + (size_t)(dt * 16 + l16) * 2048 + j0 + quad * 8);
            yacc[0][dt] = MFMA16(af, pf0, yacc[0][dt]);
            yacc[1][dt] = MFMA16(af, pf1, yacc[1][dt]);
        }
    }
    // merge the two j-group partials and transpose 64d x 16i per row-tile; store (b,t,h,d) bf16
    for (int rt = 0; rt < 2; ++rt) {
        __syncthreads();
        if (jg == 0)
            for (int dt = 0; dt < 4; ++dt)
                for (int r = 0; r < 4; ++r)
                    ytr[rwid][dt * 16 + quad * 4 + r][l16] = yacc[rt][dt][r];
        __syncthreads();
        if (jg == 1) {
            for (int dt = 0; dt < 4; ++dt)
                for (int r = 0; r < 4; ++r)
                    ytr[rwid][dt * 16 + quad * 4 + r][l16] += yacc[rt][dt][r];
        }
        __syncthreads();
        if (jg == 1) {
            for (int it = 0; it < 2; ++it) {
                int row = it * 8 + (lane >> 3);
                int dgp = (lane & 7) * 8;
                ushort8_t pk;
                for (int j = 0; j < 8; ++j) pk[j] = f2bf(ytr[rwid][dgp + j][row]);
                int t = r0 + rt * 16 + row;
                size_t oidx = ((size_t)(bb * 2048 + t) * 512) + hh * 64 + dgp;
                *(ushort8_t*)(ybuf + oidx) = pk;
            }
        }
    }
}

extern "C" void kernel_launch(void* const* d_in, const int* in_sizes, int n_in,
                              void* d_out, int out_size, void* d_ws, size_t ws_size,
                              hipStream_t stream) {
    const float* x   = (const float*)d_in[0];
    const float* dlt = (const float*)d_in[1];
    const float* qkv = (const float*)d_in[2];
    const float* g1  = (const float*)d_in[3];
    const float* g2  = (const float*)d_in[4];
    const float* g3  = (const float*)d_in[5];
    float* out = (float*)d_out;
    char* ws = (char*)d_ws;
    // workspace layout (33.5 MiB). The 8 MiB region at +1 MiB is reused thrice:
    // wb (dead after rms_prepare) -> colPart (dead after col_reduce) -> yb.
    unsigned short* W   = (unsigned short*)(ws);
    unsigned short* WT  = (unsigned short*)(ws + 524288);
    unsigned short* wb  = (unsigned short*)(ws + 1048576);
    float*          colPart = (float*)(ws + 1048576);
    unsigned short* yb  = wb;
    unsigned short* n1  = (unsigned short*)(ws + 9437184);
    unsigned short* n2  = (unsigned short*)(ws + 17825792);
    unsigned short* n3t = (unsigned short*)(ws + 26214400);
    float* rowRinv = (float*)(ws + 34603008);
    float* colRinv = (float*)(ws + 34865152);

    prep_w<<<dim3(8, 8), 256, 0, stream>>>(qkv, dlt, W, WT);
    gemm_bt<<<dim3(128, 8), 256, 0, stream>>>(x, W, wb, 8192, 512, 512, 1, 1);
    rms_prepare<<<dim3(32, 32), 256, 0, stream>>>(wb, g1, g2, g3, n1, n2, n3t);
    att_sums<<<dim3(16, 32), 512, 0, stream>>>(n1, n2, rowRinv, colPart);
    col_reduce<<<256, 256, 0, stream>>>(colPart, colRinv);
    att_apply<<<dim3(16, 32), 512, 0, stream>>>(n1, n2, n3t, rowRinv, colRinv, yb);
    gemm_bt<<<dim3(128, 8), 256, 0, stream>>>(yb, WT, out, 8192, 512, 512, 0, 0);
}